// Round 1
// baseline (754.312 us; speedup 1.0000x reference)
//
#include <hip/hip_runtime.h>

// EEGGraphClf graph-loss, fused single pass over A. B=64, N=1024, D=16.
//
// loss[b] = 0.2 * [ sum_n deg_n*||f_n||^2 - sum_j f_j . w_j ] / N^2
//         - 0.1 * sum_n log(deg_n + 1e-12) / N
//         + 0.1 * sum_{n,j} A[n,j]^2 / N^2
//   with w_j = sum_n A[n,j] * f_n   (accumulated in registers, dotted once at end)
//
// 16 blocks/batch, block = 64 rows x 1024 cols, 256 threads. Thread t owns
// cols 4t..4t+3; w[4 cols][16 floats] = 64 VGPR accumulators.
//
// R5 theory: old loop issued 4 *global* uniform loads for f_r each row after
// the A-prefetch; vmcnt is in-order, so waiting on f_r drained the A prefetch
// every iteration -> latency-bound at ~2.5x the 43us A-stream roofline.
// Fix: (a) re-associate smoothness so f_r is only a prefetchable FMA operand
// (w_j accumulation; deg_n*||f_n||^2 folded into finalize), (b) f rows staged
// once in LDS (4KB) and read via ds_read_b128 one row ahead (lgkm domain,
// decoupled from vmcnt), (c) 4-row-deep A prefetch, only VMEM in the loop.

#define NN      1024
#define DD      16
#define ROWS    64
#define TPB     256
#define SMOOTHR 0.2f
#define DEGRR   0.1f
#define SPARSR  0.1f
#define EPSV    1e-12f

typedef float vf4 __attribute__((ext_vector_type(4)));

__global__ __launch_bounds__(TPB, 4)
void graph_loss_kernel(const float* __restrict__ A,
                       const float* __restrict__ F,
                       float* __restrict__ out) {
    __shared__ float fLDS[ROWS][DD];     // 4 KB: this block's 64 row-features
    __shared__ float degq[ROWS][65];     // 16.6 KB deg group-partials, pad 65
    __shared__ float wred[4][2];

    const int tid = threadIdx.x;
    const int bid = blockIdx.x;
    const int b   = bid >> 4;
    const int n0  = (bid & 15) * ROWS;

    const float* __restrict__ Fb = F + (size_t)b * NN * DD;
    const float* __restrict__ Ab = A + ((size_t)b * NN + n0) * NN;

    // ---- stage the 64 row-features to LDS: 1024 floats = 256 threads x vf4 ----
    ((vf4*)fLDS)[tid] = *(const vf4*)(Fb + (size_t)n0 * DD + 4 * tid);
    __syncthreads();

    // ---- per-thread state ----
    vf4 w[4][4];                          // w_j accumulators: 4 own cols x 16 floats
    #pragma unroll
    for (int jj = 0; jj < 4; ++jj)
        #pragma unroll
        for (int q = 0; q < 4; ++q)
            w[jj][q] = (vf4){0.f, 0.f, 0.f, 0.f};

    float sq = 0.f;
    const float* __restrict__ arow = Ab + 4 * tid;
    const int  g       = tid >> 2;
    const bool deglane = (tid & 3) == 0;

    #define LOADR(r) __builtin_nontemporal_load((const vf4*)(arow + (size_t)(r) * NN))
    #define LDF(dst, rr)                                                     \
        do {                                                                 \
            dst##0 = *(const vf4*)&fLDS[(rr)][0];                            \
            dst##1 = *(const vf4*)&fLDS[(rr)][4];                            \
            dst##2 = *(const vf4*)&fLDS[(rr)][8];                            \
            dst##3 = *(const vf4*)&fLDS[(rr)][12];                           \
        } while (0)
    #define COMPUTE(av, f0v, f1v, f2v, f3v, rr)                              \
        do {                                                                 \
            float s_ = (av.x + av.y) + (av.z + av.w);                        \
            s_ += __shfl_xor(s_, 1);                                         \
            s_ += __shfl_xor(s_, 2);                                         \
            if (deglane) degq[(rr)][g] = s_;                                 \
            sq += av.x * av.x + av.y * av.y + av.z * av.z + av.w * av.w;     \
            w[0][0] += av.x * f0v; w[1][0] += av.y * f0v;                    \
            w[2][0] += av.z * f0v; w[3][0] += av.w * f0v;                    \
            w[0][1] += av.x * f1v; w[1][1] += av.y * f1v;                    \
            w[2][1] += av.z * f1v; w[3][1] += av.w * f1v;                    \
            w[0][2] += av.x * f2v; w[1][2] += av.y * f2v;                    \
            w[2][2] += av.z * f2v; w[3][2] += av.w * f2v;                    \
            w[0][3] += av.x * f3v; w[1][3] += av.y * f3v;                    \
            w[2][3] += av.z * f3v; w[3][3] += av.w * f3v;                    \
        } while (0)

    // ---- prologue: 4-row A prefetch, f double-buffer ----
    vf4 a0 = LOADR(0);
    vf4 a1 = LOADR(1);
    vf4 a2 = LOADR(2);
    vf4 a3 = LOADR(3);
    vf4 fA0, fA1, fA2, fA3, fB0, fB1, fB2, fB3;
    LDF(fA, 0);

    // ---- main loop: 4 rows/iter, zero barriers, only A loads on vmcnt ----
    #pragma unroll 1
    for (int r = 0; r < ROWS - 4; r += 4) {
        LDF(fB, r + 1);
        COMPUTE(a0, fA0, fA1, fA2, fA3, r);
        a0 = LOADR(r + 4);
        LDF(fA, r + 2);
        COMPUTE(a1, fB0, fB1, fB2, fB3, r + 1);
        a1 = LOADR(r + 5);
        LDF(fB, r + 3);
        COMPUTE(a2, fA0, fA1, fA2, fA3, r + 2);
        a2 = LOADR(r + 6);
        LDF(fA, r + 4);
        COMPUTE(a3, fB0, fB1, fB2, fB3, r + 3);
        a3 = LOADR(r + 7);
    }
    // tail: rows ROWS-4..ROWS-1 in a0..a3, fA holds row ROWS-4
    LDF(fB, ROWS - 3);
    COMPUTE(a0, fA0, fA1, fA2, fA3, ROWS - 4);
    LDF(fA, ROWS - 2);
    COMPUTE(a1, fB0, fB1, fB2, fB3, ROWS - 3);
    LDF(fB, ROWS - 1);
    COMPUTE(a2, fA0, fA1, fA2, fA3, ROWS - 2);
    COMPUTE(a3, fB0, fB1, fB2, fB3, ROWS - 1);

    #undef LOADR
    #undef LDF
    #undef COMPUTE

    // ---- finalize degrees: deg_n, log(deg_n), deg_n*||f_n||^2 ----
    __syncthreads();
    float lg = 0.f, dfn = 0.f;
    if (tid < ROWS) {
        float s = 0.f;
        #pragma unroll 1
        for (int i = 0; i < ROWS; ++i) s += degq[tid][i];  // stride 65: conflict-free
        lg = logf(s + EPSV);
        float t = 0.f;
        #pragma unroll
        for (int d = 0; d < DD; ++d) { const float v = fLDS[tid][d]; t += v * v; }
        dfn = s * t;
    }

    // ---- dot own columns' features against w (16 vf4 global loads, once) ----
    float dot = 0.f;
    {
        const float* p = Fb + (size_t)(4 * tid) * DD;
        #pragma unroll
        for (int jj = 0; jj < 4; ++jj)
            #pragma unroll
            for (int q = 0; q < 4; ++q) {
                const vf4 f = *(const vf4*)(p + jj * DD + 4 * q);
                dot += f.x * w[jj][q].x + f.y * w[jj][q].y
                     + f.z * w[jj][q].z + f.w * w[jj][q].w;
            }
    }

    // ---- block reduction: dot/sq across 4 waves; lg/dfn live wholly in wave 0 ----
    #pragma unroll
    for (int m = 1; m < 64; m <<= 1) {
        dot += __shfl_xor(dot, m);
        sq  += __shfl_xor(sq, m);
        lg  += __shfl_xor(lg, m);
        dfn += __shfl_xor(dfn, m);
    }
    const int wv = tid >> 6;
    if ((tid & 63) == 0) { wred[wv][0] = dot; wred[wv][1] = sq; }
    __syncthreads();
    if (tid == 0) {
        float Dt = 0.f, Q = 0.f;
        #pragma unroll
        for (int i = 0; i < 4; ++i) { Dt += wred[i][0]; Q += wred[i][1]; }
        const float denom = (float)NN * (float)NN;
        const float contrib = SMOOTHR * (dfn - Dt) / denom
                            - DEGRR * lg / (float)NN
                            + SPARSR * Q / denom;
        atomicAdd(out + b, contrib);
    }
}

extern "C" void kernel_launch(void* const* d_in, const int* in_sizes, int n_in,
                              void* d_out, int out_size, void* d_ws, size_t ws_size,
                              hipStream_t stream) {
    const float* A = (const float*)d_in[0];   // out_adj [B,N,N]
    const float* F = (const float*)d_in[1];   // features [B,N,D]
    float* out = (float*)d_out;               // [B]

    const int B = out_size;                   // 64
    (void)hipMemsetAsync(d_out, 0, (size_t)B * sizeof(float), stream);
    graph_loss_kernel<<<dim3(B * (NN / ROWS)), dim3(TPB), 0, stream>>>(A, F, out);
}

// Round 2
// 443.559 us; speedup vs baseline: 1.7006x; 1.7006x over previous
//
#include <hip/hip_runtime.h>

// EEGGraphClf graph-loss, fused single pass over A. B=64, N=1024, D=16.
//
// loss[b] = 0.2 * [ sum_n deg_n*||f_n||^2 - sum_j f_j . w_j ] / N^2
//         - 0.1 * sum_n log(deg_n + 1e-12) / N
//         + 0.1 * sum_{n,j} A[n,j]^2 / N^2
//   with w_j = sum_n A[n,j] * f_n   (register accumulators, dotted once at end)
//
// 16 blocks/batch, block = 64 rows x 1024 cols, 512 threads. Thread t owns
// cols 2t..2t+1 -> w[2 cols][16 floats] = 32 VGPR accumulators.
//
// R5 lesson (counter evidence): launch_bounds(256,4) + ~140-reg live set ->
// compiler spilled w to scratch: WRITE_SIZE 1.06 GB/dispatch (kernel writes
// 256 B), FETCH 700 MB vs 262 MB ideal, 476us. The fix is not to drop the
// occupancy bound but to shrink the live set: 2 cols/thread halves w to 32
// regs; total live ~90 < 128-reg cap -> no spill AND 4 waves/SIMD.
// Structure kept from R5: f rows staged once in LDS (lgkm domain, decoupled
// from the vmcnt A-stream), f double-buffered in regs, 4-row A prefetch,
// zero barriers in the main loop.

#define NN      1024
#define DD      16
#define ROWS    64
#define TPB     512
#define SMOOTHR 0.2f
#define DEGRR   0.1f
#define SPARSR  0.1f
#define EPSV    1e-12f

typedef float vf4 __attribute__((ext_vector_type(4)));
typedef float vf2 __attribute__((ext_vector_type(2)));

__global__ __launch_bounds__(TPB, 4)
void graph_loss_kernel(const float* __restrict__ A,
                       const float* __restrict__ F,
                       float* __restrict__ out) {
    __shared__ float fLDS[ROWS][DD];     // 4 KB: this block's 64 row-features
    __shared__ float degq[ROWS][65];     // 16.6 KB deg group-partials, pad 65
    __shared__ float wred[8][2];

    const int tid = threadIdx.x;
    const int bid = blockIdx.x;
    const int b   = bid >> 4;
    const int n0  = (bid & 15) * ROWS;

    const float* __restrict__ Fb = F + (size_t)b * NN * DD;
    const float* __restrict__ Ab = A + ((size_t)b * NN + n0) * NN;

    // ---- stage the 64 row-features to LDS: 1024 floats = 256 threads x vf4 ----
    if (tid < 256)
        ((vf4*)fLDS)[tid] = *(const vf4*)(Fb + (size_t)n0 * DD + 4 * tid);
    __syncthreads();

    // ---- per-thread state: w[col][quad] = 8 vf4 = 32 VGPR ----
    vf4 w[2][4];
    #pragma unroll
    for (int jj = 0; jj < 2; ++jj)
        #pragma unroll
        for (int q = 0; q < 4; ++q)
            w[jj][q] = (vf4){0.f, 0.f, 0.f, 0.f};

    float sq = 0.f;
    const float* __restrict__ arow = Ab + 2 * tid;
    const int  g       = tid >> 3;           // 8 threads = 16 cols per group
    const bool deglane = (tid & 7) == 0;

    #define LOADR(r) __builtin_nontemporal_load((const vf2*)(arow + (size_t)(r) * NN))
    #define LDF(dst, rr)                                                     \
        do {                                                                 \
            dst##0 = *(const vf4*)&fLDS[(rr)][0];                            \
            dst##1 = *(const vf4*)&fLDS[(rr)][4];                            \
            dst##2 = *(const vf4*)&fLDS[(rr)][8];                            \
            dst##3 = *(const vf4*)&fLDS[(rr)][12];                           \
        } while (0)
    #define COMPUTE(av, f0v, f1v, f2v, f3v, rr)                              \
        do {                                                                 \
            float s_ = av.x + av.y;                                          \
            s_ += __shfl_xor(s_, 1);                                         \
            s_ += __shfl_xor(s_, 2);                                         \
            s_ += __shfl_xor(s_, 4);                                         \
            if (deglane) degq[(rr)][g] = s_;                                 \
            sq += av.x * av.x + av.y * av.y;                                 \
            w[0][0] += av.x * f0v;  w[1][0] += av.y * f0v;                   \
            w[0][1] += av.x * f1v;  w[1][1] += av.y * f1v;                   \
            w[0][2] += av.x * f2v;  w[1][2] += av.y * f2v;                   \
            w[0][3] += av.x * f3v;  w[1][3] += av.y * f3v;                   \
        } while (0)

    // ---- prologue: 4-row A prefetch, f double-buffer ----
    vf2 a0 = LOADR(0);
    vf2 a1 = LOADR(1);
    vf2 a2 = LOADR(2);
    vf2 a3 = LOADR(3);
    vf4 fA0, fA1, fA2, fA3, fB0, fB1, fB2, fB3;
    LDF(fA, 0);

    // ---- main loop: 4 rows/iter, zero barriers, only A loads on vmcnt ----
    #pragma unroll 1
    for (int r = 0; r < ROWS - 4; r += 4) {
        LDF(fB, r + 1);
        COMPUTE(a0, fA0, fA1, fA2, fA3, r);
        a0 = LOADR(r + 4);
        LDF(fA, r + 2);
        COMPUTE(a1, fB0, fB1, fB2, fB3, r + 1);
        a1 = LOADR(r + 5);
        LDF(fB, r + 3);
        COMPUTE(a2, fA0, fA1, fA2, fA3, r + 2);
        a2 = LOADR(r + 6);
        LDF(fA, r + 4);
        COMPUTE(a3, fB0, fB1, fB2, fB3, r + 3);
        a3 = LOADR(r + 7);
    }
    // tail: rows ROWS-4..ROWS-1 in a0..a3, fA holds row ROWS-4
    LDF(fB, ROWS - 3);
    COMPUTE(a0, fA0, fA1, fA2, fA3, ROWS - 4);
    LDF(fA, ROWS - 2);
    COMPUTE(a1, fB0, fB1, fB2, fB3, ROWS - 3);
    LDF(fB, ROWS - 1);
    COMPUTE(a2, fA0, fA1, fA2, fA3, ROWS - 2);
    COMPUTE(a3, fB0, fB1, fB2, fB3, ROWS - 1);

    #undef LOADR
    #undef LDF
    #undef COMPUTE

    // ---- finalize degrees: deg_n, log(deg_n), deg_n*||f_n||^2 (wave 0 only) ----
    __syncthreads();
    float lg = 0.f, dfn = 0.f;
    if (tid < ROWS) {
        float s = 0.f;
        #pragma unroll 1
        for (int i = 0; i < ROWS; ++i) s += degq[tid][i];  // stride 65: conflict-free
        lg = logf(s + EPSV);
        float t = 0.f;
        #pragma unroll
        for (int d = 0; d < DD; ++d) { const float v = fLDS[tid][d]; t += v * v; }
        dfn = s * t;
    }

    // ---- dot own columns' features against w (8 vf4 global loads, once) ----
    float dot = 0.f;
    {
        const float* p = Fb + (size_t)(2 * tid) * DD;
        #pragma unroll
        for (int jj = 0; jj < 2; ++jj)
            #pragma unroll
            for (int q = 0; q < 4; ++q) {
                const vf4 f = *(const vf4*)(p + jj * DD + 4 * q);
                dot += f.x * w[jj][q].x + f.y * w[jj][q].y
                     + f.z * w[jj][q].z + f.w * w[jj][q].w;
            }
    }

    // ---- block reduction: dot/sq across 8 waves; lg/dfn live wholly in wave 0 ----
    #pragma unroll
    for (int m = 1; m < 64; m <<= 1) {
        dot += __shfl_xor(dot, m);
        sq  += __shfl_xor(sq, m);
        lg  += __shfl_xor(lg, m);
        dfn += __shfl_xor(dfn, m);
    }
    const int wv = tid >> 6;
    if ((tid & 63) == 0) { wred[wv][0] = dot; wred[wv][1] = sq; }
    __syncthreads();
    if (tid == 0) {
        float Dt = 0.f, Q = 0.f;
        #pragma unroll
        for (int i = 0; i < 8; ++i) { Dt += wred[i][0]; Q += wred[i][1]; }
        const float denom = (float)NN * (float)NN;
        const float contrib = SMOOTHR * (dfn - Dt) / denom
                            - DEGRR * lg / (float)NN
                            + SPARSR * Q / denom;
        atomicAdd(out + b, contrib);
    }
}

extern "C" void kernel_launch(void* const* d_in, const int* in_sizes, int n_in,
                              void* d_out, int out_size, void* d_ws, size_t ws_size,
                              hipStream_t stream) {
    const float* A = (const float*)d_in[0];   // out_adj [B,N,N]
    const float* F = (const float*)d_in[1];   // features [B,N,D]
    float* out = (float*)d_out;               // [B]

    const int B = out_size;                   // 64
    (void)hipMemsetAsync(d_out, 0, (size_t)B * sizeof(float), stream);
    graph_loss_kernel<<<dim3(B * (NN / ROWS)), dim3(TPB), 0, stream>>>(A, F, out);
}

// Round 3
// 365.766 us; speedup vs baseline: 2.0623x; 1.2127x over previous
//
#include <hip/hip_runtime.h>

// EEGGraphClf graph-loss, fused single pass over A. B=64, N=1024, D=16.
//
// loss[b] = 0.2 * [ sum_n deg_n*||f_n||^2 - sum_j f_j . w_j ] / N^2
//         - 0.1 * sum_n log(deg_n + 1e-12) / N
//         + 0.1 * sum_{n,j} A[n,j]^2 / N^2
//   with w_j = sum_n A[n,j] * f_n   (register accumulators, dotted once at end)
//
// 16 blocks/batch, block = 64 rows x 1024 cols, 512 threads, 2 cols/thread.
//
// R2 counter evidence: VALUBusy 15%, BW 19%, Occ 40% -> latency-chain bound.
// Cause: 8 DS ops/row/wave (4 ds_read_b128 f-loads + 3 dependent ds_swizzle
// + write) = serial lgkm chain per row + ~37% raw DS-pipe occupancy.
// R3: f comes from wave-UNIFORM loads -> compiler scalarizes to s_load
// (SMEM, SGPRs: no DS ops, no VGPR cost, not on vmcnt — R0 proved this);
// deg shfl chain cut 3->2 swizzles (4-thread partials, degq[64][129]);
// loop VGPR live set ~55-60 -> 8 waves/SIMD, 4 blocks/CU resident.
// Only vmcnt traffic: 4-row-deep nontemporal A prefetch.

#define NN      1024
#define DD      16
#define ROWS    64
#define TPB     512
#define GRPS    128        // 512 threads / 4 = 128 deg groups per row
#define SMOOTHR 0.2f
#define DEGRR   0.1f
#define SPARSR  0.1f
#define EPSV    1e-12f

typedef float vf4 __attribute__((ext_vector_type(4)));
typedef float vf2 __attribute__((ext_vector_type(2)));

__global__ __launch_bounds__(TPB, 4)
void graph_loss_kernel(const float* __restrict__ A,
                       const float* __restrict__ F,
                       float* __restrict__ out) {
    __shared__ float degq[ROWS][GRPS + 1];   // 33 KB, stride 129: (tid+i)%32 banks
    __shared__ float wred[8][2];

    const int tid = threadIdx.x;
    const int bid = blockIdx.x;
    const int b   = bid >> 4;
    const int n0  = (bid & 15) * ROWS;

    const float* __restrict__ Fb = F + (size_t)b * NN * DD;
    const float* __restrict__ Ab = A + ((size_t)b * NN + n0) * NN;

    // ---- per-thread state: w[col][quad] = 8 vf4 = 32 VGPR ----
    vf4 w[2][4];
    #pragma unroll
    for (int jj = 0; jj < 2; ++jj)
        #pragma unroll
        for (int q = 0; q < 4; ++q)
            w[jj][q] = (vf4){0.f, 0.f, 0.f, 0.f};

    float sq = 0.f;
    const float* __restrict__ arow = Ab + 2 * tid;
    const int  g       = tid >> 2;           // 4 threads = 8 cols per group
    const bool deglane = (tid & 3) == 0;

    #define LOADR(r) __builtin_nontemporal_load((const vf2*)(arow + (size_t)(r) * NN))
    // wave-uniform row features -> scalar s_load into SGPRs (no DS, no vmcnt)
    #define LDF(dst, rr)                                                     \
        do {                                                                 \
            const vf4* __restrict__ Fr =                                     \
                (const vf4*)(Fb + (size_t)(n0 + (rr)) * DD);                 \
            dst##0 = Fr[0]; dst##1 = Fr[1]; dst##2 = Fr[2]; dst##3 = Fr[3];  \
        } while (0)
    #define COMPUTE(av, f0v, f1v, f2v, f3v, rr)                              \
        do {                                                                 \
            float s_ = av.x + av.y;                                          \
            s_ += __shfl_xor(s_, 1);                                         \
            s_ += __shfl_xor(s_, 2);                                         \
            if (deglane) degq[(rr)][g] = s_;                                 \
            sq += av.x * av.x + av.y * av.y;                                 \
            w[0][0] += av.x * f0v;  w[1][0] += av.y * f0v;                   \
            w[0][1] += av.x * f1v;  w[1][1] += av.y * f1v;                   \
            w[0][2] += av.x * f2v;  w[1][2] += av.y * f2v;                   \
            w[0][3] += av.x * f3v;  w[1][3] += av.y * f3v;                   \
        } while (0)

    // ---- prologue: 4-row A prefetch, f double-buffer (SGPRs) ----
    vf2 a0 = LOADR(0);
    vf2 a1 = LOADR(1);
    vf2 a2 = LOADR(2);
    vf2 a3 = LOADR(3);
    vf4 fA0, fA1, fA2, fA3, fB0, fB1, fB2, fB3;
    LDF(fA, 0);

    // ---- main loop: 4 rows/iter, zero barriers, only A loads on vmcnt ----
    #pragma unroll 1
    for (int r = 0; r < ROWS - 4; r += 4) {
        LDF(fB, r + 1);
        COMPUTE(a0, fA0, fA1, fA2, fA3, r);
        a0 = LOADR(r + 4);
        LDF(fA, r + 2);
        COMPUTE(a1, fB0, fB1, fB2, fB3, r + 1);
        a1 = LOADR(r + 5);
        LDF(fB, r + 3);
        COMPUTE(a2, fA0, fA1, fA2, fA3, r + 2);
        a2 = LOADR(r + 6);
        LDF(fA, r + 4);
        COMPUTE(a3, fB0, fB1, fB2, fB3, r + 3);
        a3 = LOADR(r + 7);
    }
    // tail: rows ROWS-4..ROWS-1 in a0..a3, fA holds row ROWS-4
    LDF(fB, ROWS - 3);
    COMPUTE(a0, fA0, fA1, fA2, fA3, ROWS - 4);
    LDF(fA, ROWS - 2);
    COMPUTE(a1, fB0, fB1, fB2, fB3, ROWS - 3);
    LDF(fB, ROWS - 1);
    COMPUTE(a2, fA0, fA1, fA2, fA3, ROWS - 2);
    COMPUTE(a3, fB0, fB1, fB2, fB3, ROWS - 1);

    #undef LOADR
    #undef LDF
    #undef COMPUTE

    // ---- finalize degrees: deg_n, log(deg_n), deg_n*||f_n||^2 (wave 0 only) ----
    __syncthreads();
    float lg = 0.f, dfn = 0.f;
    if (tid < ROWS) {
        float s = 0.f;
        #pragma unroll 1
        for (int i = 0; i < GRPS; ++i) s += degq[tid][i];  // stride 129: 2 lanes/bank
        lg = logf(s + EPSV);
        const float* p = Fb + (size_t)(n0 + tid) * DD;
        float t = 0.f;
        #pragma unroll
        for (int q = 0; q < 4; ++q) {
            const vf4 f = *(const vf4*)(p + 4 * q);
            t += f.x * f.x + f.y * f.y + f.z * f.z + f.w * f.w;
        }
        dfn = s * t;
    }

    // ---- dot own columns' features against w (8 vf4 global loads, once) ----
    float dot = 0.f;
    {
        const float* p = Fb + (size_t)(2 * tid) * DD;
        #pragma unroll
        for (int jj = 0; jj < 2; ++jj)
            #pragma unroll
            for (int q = 0; q < 4; ++q) {
                const vf4 f = *(const vf4*)(p + jj * DD + 4 * q);
                dot += f.x * w[jj][q].x + f.y * w[jj][q].y
                     + f.z * w[jj][q].z + f.w * w[jj][q].w;
            }
    }

    // ---- block reduction: dot/sq across 8 waves; lg/dfn live wholly in wave 0 ----
    #pragma unroll
    for (int m = 1; m < 64; m <<= 1) {
        dot += __shfl_xor(dot, m);
        sq  += __shfl_xor(sq, m);
        lg  += __shfl_xor(lg, m);
        dfn += __shfl_xor(dfn, m);
    }
    const int wv = tid >> 6;
    if ((tid & 63) == 0) { wred[wv][0] = dot; wred[wv][1] = sq; }
    __syncthreads();
    if (tid == 0) {
        float Dt = 0.f, Q = 0.f;
        #pragma unroll
        for (int i = 0; i < 8; ++i) { Dt += wred[i][0]; Q += wred[i][1]; }
        const float denom = (float)NN * (float)NN;
        const float contrib = SMOOTHR * (dfn - Dt) / denom
                            - DEGRR * lg / (float)NN
                            + SPARSR * Q / denom;
        atomicAdd(out + b, contrib);
    }
}

extern "C" void kernel_launch(void* const* d_in, const int* in_sizes, int n_in,
                              void* d_out, int out_size, void* d_ws, size_t ws_size,
                              hipStream_t stream) {
    const float* A = (const float*)d_in[0];   // out_adj [B,N,N]
    const float* F = (const float*)d_in[1];   // features [B,N,D]
    float* out = (float*)d_out;               // [B]

    const int B = out_size;                   // 64
    (void)hipMemsetAsync(d_out, 0, (size_t)B * sizeof(float), stream);
    graph_loss_kernel<<<dim3(B * (NN / ROWS)), dim3(TPB), 0, stream>>>(A, F, out);
}